// Round 1
// 473.360 us; speedup vs baseline: 1.2971x; 1.2971x over previous
//
#include <hip/hip_runtime.h>
#include <stdint.h>

// Problem dims (fixed by reference): B=8, S=1024, D=1024, H=16, HD=64.
#define BB 8
#define SS 1024
#define DD 1024
#define HH 16
#define HDIM 64

typedef _Float16 half8 __attribute__((ext_vector_type(8)));
typedef _Float16 half4 __attribute__((ext_vector_type(4)));
typedef float   float4v __attribute__((ext_vector_type(4)));
typedef float   float8v __attribute__((ext_vector_type(8)));

#define AS1(p) ((__attribute__((address_space(1))) void*)(p))
#define AS3(p) ((__attribute__((address_space(3))) void*)(p))

#define LOG2E 1.4426950408889634f

#if __has_builtin(__builtin_amdgcn_exp2f)
#define EXP2(x) __builtin_amdgcn_exp2f(x)
#else
#define EXP2(x) __expf((x) * 0.6931471805599453f)
#endif

// ---------------------------------------------------------------------------
// f32 -> f16 conversion, multi-segment (grid.y selects segment).
// scaled[seg] != 0 => multiply by (1 - sigmoid(alp[0])) * log2(e)
// (syn pre-blend scale; log2e folds softmax into exp2 domain)
// ---------------------------------------------------------------------------
struct CvtArgs {
    const float* src[6];
    _Float16*    dst[6];
    long long    n[6];
    int          scaled[6];
    const float* alp;
};

__global__ __launch_bounds__(256) void cvt_f32_f16(CvtArgs a) {
    int seg = blockIdx.y;
    long long base = ((long long)blockIdx.x * 256 + threadIdx.x) * 8;
    if (base >= a.n[seg]) return;
    float s = 1.0f;
    if (a.scaled[seg]) s = (1.0f - 1.0f / (1.0f + __expf(-a.alp[0]))) * LOG2E;
    float8v u = *(const float8v*)(a.src[seg] + base);
    half8 h;
#pragma unroll
    for (int i = 0; i < 8; ++i) h[i] = (_Float16)(u[i] * s);
    *(half8*)(a.dst[seg] + base) = h;
}

// ---------------------------------------------------------------------------
// Pack mask (B,S,S) int32 -> bitmask (B,S,S/64) u64. One wave packs 64 keys.
// ---------------------------------------------------------------------------
__global__ __launch_bounds__(256) void pack_mask(const int* __restrict__ mask,
                                                 unsigned long long* __restrict__ bits) {
    long long gid = (long long)blockIdx.x * 256 + threadIdx.x;
    int m = mask[gid];
    unsigned long long bal = __ballot(m != 0);
    if ((threadIdx.x & 63) == 0) bits[gid >> 6] = bal;
}

// ---------------------------------------------------------------------------
// GEMM: C[m,n] = sum_k A[m,k]*W[n,k] + bias[n]   (A: Mx1024 f16, W: 1024x1024 f16)
// m97 recipe: 128x128 tile, BK=64, 4 waves (2x2 of 64x64), 16x16x32 f16 MFMA.
// MODE 0: out f16 (B,H,S,HD) linear; SCALEQ multiplies by sigmoid(alp)/8*log2e (q)
// MODE 1: out f16 V tiled+swizzled: (bh,tile)[8KB], off=((hd*128+sc*2)^((hd&15)<<3))
// MODE 2: out f32 row-major (M x 1024)  (final output projection -> d_out)
// MODE 3: out f16 K tiled+swizzled: (bh,tile)[8KB], off=((key*128+hd*2)^((key&7)<<4))
// Tiled layouts are consumed by attn's global_load_lds (linear DMA) + swizzled
// ds_read: the global image must equal the desired LDS image (both-sides rule).
// ---------------------------------------------------------------------------
template <int MODE, bool SCALEQ>
__global__ __launch_bounds__(256) void gemm_bt(
    const _Float16* __restrict__ A,
    const _Float16* __restrict__ W,
    const float* __restrict__ bias,
    void* __restrict__ out,
    const float* __restrict__ alp)
{
    constexpr int K = 1024, BM = 128, BK = 64;
    __shared__ _Float16 As[BM * BK];
    __shared__ _Float16 Bs[BM * BK];

    const int tid  = threadIdx.x;
    const int lane = tid & 63;
    const int wave = tid >> 6;
    const int wm = wave >> 1, wn = wave & 1;
    const int m0 = blockIdx.x * BM;
    const int n0 = blockIdx.y * BM;

    float4v acc[4][4] = {};

    for (int kt = 0; kt < K; kt += BK) {
#pragma unroll
        for (int i = 0; i < 4; ++i) {
            int flat = ((wave * 4 + i) * 64 + lane) * 8;  // element index in tile
            int r = flat >> 6, c = flat & 63;
            const _Float16* ga = A + (long long)(m0 + r) * K + kt + c;
            const _Float16* gb = W + (long long)(n0 + r) * K + kt + c;
            __builtin_amdgcn_global_load_lds(AS1(ga), AS3(&As[flat]), 16, 0, 0);
            __builtin_amdgcn_global_load_lds(AS1(gb), AS3(&Bs[flat]), 16, 0, 0);
        }
        __syncthreads();
#pragma unroll
        for (int kk = 0; kk < BK; kk += 32) {
            half8 af[4], bf[4];
#pragma unroll
            for (int t = 0; t < 4; ++t) {
                af[t] = *(const half8*)&As[(wm * 64 + t * 16 + (lane & 15)) * BK + kk + (lane >> 4) * 8];
                bf[t] = *(const half8*)&Bs[(wn * 64 + t * 16 + (lane & 15)) * BK + kk + (lane >> 4) * 8];
            }
#pragma unroll
            for (int mt = 0; mt < 4; ++mt)
#pragma unroll
                for (int nt = 0; nt < 4; ++nt)
                    acc[mt][nt] = __builtin_amdgcn_mfma_f32_16x16x32_f16(af[mt], bf[nt], acc[mt][nt], 0, 0, 0);
        }
        __syncthreads();
    }

    float qscale = 1.0f;
    if constexpr (SCALEQ) qscale = 0.125f * LOG2E / (1.0f + __expf(-alp[0]));

    // Epilogue. C/D layout: row = (lane>>4)*4 + reg, col = lane&15.
#pragma unroll
    for (int mt = 0; mt < 4; ++mt) {
#pragma unroll
        for (int nt = 0; nt < 4; ++nt) {
            int n  = n0 + wn * 64 + nt * 16 + (lane & 15);
            int mb = m0 + wm * 64 + mt * 16 + (lane >> 4) * 4;
            float bn = bias[n];
            if constexpr (MODE == 0) {
                _Float16* o = (_Float16*)out;
                int b = mb >> 10, s = mb & 1023, h = n >> 6, hd = n & 63;
                long long idx = ((long long)(b * 16 + h) * 1024 + s) * 64 + hd;
#pragma unroll
                for (int i = 0; i < 4; ++i)
                    o[idx + (long long)i * 64] = (_Float16)((acc[mt][nt][i] + bn) * qscale);
            } else if constexpr (MODE == 1) {
                _Float16* o = (_Float16*)out;
                int b = mb >> 10, s = mb & 1023, h = n >> 6, hd = n & 63;
                long long tbase = (((long long)(b * 16 + h)) * 16 + (s >> 6)) * 4096;
                int off = ((hd * 128 + (s & 63) * 2) ^ ((hd & 15) << 3)) >> 1;
                half4 hv;
#pragma unroll
                for (int i = 0; i < 4; ++i) hv[i] = (_Float16)(acc[mt][nt][i] + bn);
                *(half4*)&o[tbase + off] = hv;   // 8B-aligned; swizzle bits >=3 preserve it
            } else if constexpr (MODE == 3) {
                _Float16* o = (_Float16*)out;
                int b = mb >> 10, s = mb & 1023, h = n >> 6, hd = n & 63;
                long long tbase = (((long long)(b * 16 + h)) * 16 + (s >> 6)) * 4096;
#pragma unroll
                for (int i = 0; i < 4; ++i) {
                    int key = (s & 63) + i;   // s%4==0, stays within tile
                    o[tbase + (((key * 128 + hd * 2) ^ ((key & 7) << 4)) >> 1)] =
                        (_Float16)(acc[mt][nt][i] + bn);
                }
            } else {
                float* o = (float*)out;  // f32 d_out
#pragma unroll
                for (int i = 0; i < 4; ++i)
                    o[(long long)(mb + i) * 1024 + n] = acc[mt][nt][i] + bn;
            }
        }
    }
}

// ---------------------------------------------------------------------------
// Flash attention. Grid: 1024 blocks (XCD-swizzled: each XCD owns one batch),
// 4 waves/block, each wave owns 32 q-rows. K/V tiles (8KB each) staged in LDS
// via global_load_lds, double-buffered, shared by all 4 waves; one barrier per
// tile (T3 minimum 2-phase). syn+mask register-prefetched one tile ahead.
// Softmax in exp2 domain (log2e pre-folded); syn enters as QK^T MFMA C-in;
// row-sum l accumulated by a ones-column MFMA (lands in o-layout, no shfl);
// defer-max (THR=8) skips O-rescale when the running max doesn't grow.
// ---------------------------------------------------------------------------
__global__ __launch_bounds__(256) void attn_kernel(
    const _Float16* __restrict__ qw,   // (B*H, S, HD) f16 linear, pre-scaled
    const _Float16* __restrict__ ktl,  // (B*H, 16, 4096) K tiled+swizzled
    const _Float16* __restrict__ vtl,  // (B*H, 16, 4096) V tiled+swizzled
    const unsigned long long* __restrict__ mbits, // (B, S, 16) packed mask
    const _Float16* __restrict__ synh, // (H, S, S) f16, pre-scaled
    _Float16* __restrict__ ao)         // (B, S, D) f16
{
    __shared__ __align__(16) _Float16 KsA[4096];
    __shared__ __align__(16) _Float16 VsA[4096];
    __shared__ __align__(16) _Float16 KsB[4096];
    __shared__ __align__(16) _Float16 VsB[4096];

    const int tid  = threadIdx.x;
    const int lane = tid & 63;
    const int wave = tid >> 6;
    // XCD swizzle (1024 blocks, 1024%8==0 -> bijective): XCD x gets batch x.
    const int bid  = ((blockIdx.x & 7) << 7) | (blockIdx.x >> 3);
    const int b  = bid >> 7;
    const int h  = (bid >> 3) & 15;
    const int q0 = (bid & 7) * 128 + wave * 32;
    const int bh = b * 16 + h;

    // Q fragments (B-operand of 16x16x32): lane holds Q[q0+f*16+(l&15)][(l>>4)*8+j]
    half8 qf[2][2];
#pragma unroll
    for (int f = 0; f < 2; ++f) {
        const _Float16* qb = qw + ((long long)bh * SS + q0 + f * 16 + (lane & 15)) * HDIM + (lane >> 4) * 8;
        qf[f][0] = *(const half8*)qb;
        qf[f][1] = *(const half8*)(qb + 32);
    }

    float4v o[2][4] = {};
    float4v ol[2]   = {};                 // running l, already in o-layout (row i)
    float mrun[2] = {-3e38f, -3e38f};

    const _Float16* kgb = ktl + (long long)bh * 16 * 4096;
    const _Float16* vgb = vtl + (long long)bh * 16 * 4096;
    const unsigned long long* mb0 = mbits + ((long long)b * SS + q0 + (lane & 15)) * 16;
    const _Float16* syn0 = synh + ((long long)h * SS + q0 + (lane & 15)) * SS + ((lane >> 4) << 2);
    const _Float16* syn1 = syn0 + 16 * (long long)SS;

    const int tid8 = tid * 8;

    // Lane-constant swizzled LDS read offsets (halfword units).
    // K rows: key = ks*16+(l&15) -> key&7 == l&7 (lane-constant). 2-way max (free).
    const int kswz = (lane & 7) << 4;
    const int kb0h = (((((lane & 15) << 7) + ((lane >> 4) << 4))      ) ^ kswz) >> 1;
    const int kb1h = (((((lane & 15) << 7) + ((lane >> 4) << 4)) + 64 ) ^ kswz) >> 1;
    // V rows: hd = n*16+(l&15) -> hd&15 == l&15 (n-independent). Conflict-free.
    int vbh[4];
#pragma unroll
    for (int ks = 0; ks < 4; ++ks)
        vbh[ks] = ((((lane & 15) << 7) + ks * 32 + ((lane >> 4) << 3)) ^ ((lane & 15) << 3)) >> 1;

    auto stage = [&](_Float16* Ksb, _Float16* Vsb, int t) {
        const _Float16* kg = kgb + t * 4096 + tid8;
        const _Float16* vg = vgb + t * 4096 + tid8;
        __builtin_amdgcn_global_load_lds(AS1(kg),        AS3(Ksb + tid8),        16, 0, 0);
        __builtin_amdgcn_global_load_lds(AS1(kg + 2048), AS3(Ksb + tid8 + 2048), 16, 0, 0);
        __builtin_amdgcn_global_load_lds(AS1(vg),        AS3(Vsb + tid8),        16, 0, 0);
        __builtin_amdgcn_global_load_lds(AS1(vg + 2048), AS3(Vsb + tid8 + 2048), 16, 0, 0);
    };

    half4 svA[2][4], svB[2][4];
    unsigned long long btA[2], btB[2];

    auto loadSyn = [&](int t, half4 (&sv)[2][4], unsigned long long (&bt)[2]) {
        bt[0] = mb0[t];
        bt[1] = mb0[256 + t];
        const int kb = t << 6;
#pragma unroll
        for (int ks = 0; ks < 4; ++ks) {
            sv[0][ks] = *(const half4*)(syn0 + kb + ks * 16);
            sv[1][ks] = *(const half4*)(syn1 + kb + ks * 16);
        }
    };

    const half4 vone = {(_Float16)1.f, (_Float16)1.f, (_Float16)1.f, (_Float16)1.f};

    auto compute = [&](const _Float16 (&Ks)[4096], const _Float16 (&Vs)[4096],
                       half4 (&sv)[2][4], unsigned long long (&bt)[2]) {
        // QK^T with syn as C-in. S^T frag == A-frag of PV (16x16x16).
        float4v st[2][4];
#pragma unroll
        for (int ks = 0; ks < 4; ++ks) {
            half8 k0 = *(const half8*)&Ks[kb0h + ks * 1024];
            half8 k1 = *(const half8*)&Ks[kb1h + ks * 1024];
#pragma unroll
            for (int f = 0; f < 2; ++f) {
                float4v s;
#pragma unroll
                for (int i = 0; i < 4; ++i) s[i] = (float)sv[f][ks][i];
                s = __builtin_amdgcn_mfma_f32_16x16x32_f16(k0, qf[f][0], s, 0, 0, 0);
                s = __builtin_amdgcn_mfma_f32_16x16x32_f16(k1, qf[f][1], s, 0, 0, 0);
                st[f][ks] = s;   // S[q=l&15][key = ks*16+(l>>4)*4+i]  (log2 domain)
            }
        }
        half4 pf[2][4];
#pragma unroll
        for (int f = 0; f < 2; ++f) {
            const unsigned long long bits = bt[f];
            float tmax = -3e38f;
#pragma unroll
            for (int ks = 0; ks < 4; ++ks)
#pragma unroll
                for (int i = 0; i < 4; ++i) {
                    int pos = ks * 16 + ((lane >> 4) << 2) + i;
                    float sc = ((bits >> pos) & 1ull) ? st[f][ks][i] : -1e9f;
                    st[f][ks][i] = sc;
                    tmax = fmaxf(tmax, sc);
                }
            tmax = fmaxf(tmax, __shfl_xor(tmax, 16));
            tmax = fmaxf(tmax, __shfl_xor(tmax, 32));
            // defer-max: only rescale when max grows by > 8 (p bounded by 2^8).
            if (__any(tmax > mrun[f] + 8.0f)) {
                float mnew = fmaxf(mrun[f], tmax);
                float corr = EXP2(mrun[f] - mnew);
                float cr[4];
#pragma unroll
                for (int i = 0; i < 4; ++i) cr[i] = __shfl(corr, ((lane >> 4) << 2) + i);
#pragma unroll
                for (int n = 0; n < 4; ++n)
#pragma unroll
                    for (int i = 0; i < 4; ++i) o[f][n][i] *= cr[i];
#pragma unroll
                for (int i = 0; i < 4; ++i) ol[f][i] *= cr[i];
                mrun[f] = mnew;
            }
#pragma unroll
            for (int ks = 0; ks < 4; ++ks)
#pragma unroll
                for (int i = 0; i < 4; ++i)
                    pf[f][ks][i] = (_Float16)EXP2(st[f][ks][i] - mrun[f]);
        }
        // PV + ones-column row-sum. vf shared by both q-fragments.
#pragma unroll
        for (int ks = 0; ks < 4; ++ks) {
            ol[0] = __builtin_amdgcn_mfma_f32_16x16x16f16(pf[0][ks], vone, ol[0], 0, 0, 0);
            ol[1] = __builtin_amdgcn_mfma_f32_16x16x16f16(pf[1][ks], vone, ol[1], 0, 0, 0);
#pragma unroll
            for (int n = 0; n < 4; ++n) {
                half4 vf = *(const half4*)&Vs[vbh[ks] + n * 1024];
                o[0][n] = __builtin_amdgcn_mfma_f32_16x16x16f16(pf[0][ks], vf, o[0][n], 0, 0, 0);
                o[1][n] = __builtin_amdgcn_mfma_f32_16x16x16f16(pf[1][ks], vf, o[1][n], 0, 0, 0);
            }
        }
    };

    stage(KsA, VsA, 0);
    loadSyn(0, svA, btA);
    __syncthreads();                 // tile 0 staged (barrier drains vmcnt)

    for (int t = 0; t < 16; t += 2) {
        stage(KsB, VsB, t + 1);      // DMA t+1 overlaps compute of t
        loadSyn(t + 1, svB, btB);
        compute(KsA, VsA, svA, btA);
        __syncthreads();             // t+1 ready; everyone done with A
        if (t + 2 < 16) {
            stage(KsA, VsA, t + 2);
            loadSyn(t + 2, svA, btA);
        }
        compute(KsB, VsB, svB, btB);
        __syncthreads();
    }

    // Epilogue: l already in o-layout -> no shuffles.
#pragma unroll
    for (int f = 0; f < 2; ++f) {
        float inv[4];
#pragma unroll
        for (int i = 0; i < 4; ++i) inv[i] = 1.0f / ol[f][i];
#pragma unroll
        for (int n = 0; n < 4; ++n)
#pragma unroll
            for (int i = 0; i < 4; ++i) {
                int qrow = q0 + f * 16 + (lane >> 4) * 4 + i;
                long long idx = ((long long)b * SS + qrow) * DD + h * 64 + n * 16 + (lane & 15);
                ao[idx] = (_Float16)(o[f][n][i] * inv[i]);
            }
    }
}

// ---------------------------------------------------------------------------
// Launcher. ws layout (f16 elements):
//   [0,8M)     xbuf (converted query/key_in/value; later ao)
//   [8M,12M)   Wq,Wk,Wv,Wo f16 (1M each)
//   [12M,20M)  q  (B,H,S,HD)   pre-scaled by sigmoid(alpha)/8*log2e
//   [20M,28M)  k  tiled+swizzled (B*H,16,4096)
//   [28M,36M)  vT tiled+swizzled (B*H,16,4096)
//   [36M,52M)  synh (H,S,S) f16 pre-scaled by (1-alpha)*log2e
//   [52M,+1MB) mbits (B,S,16) u64
// ---------------------------------------------------------------------------
extern "C" void kernel_launch(void* const* d_in, const int* in_sizes, int n_in,
                              void* d_out, int out_size, void* d_ws, size_t ws_size,
                              hipStream_t stream) {
    const float* query  = (const float*)d_in[0];
    const float* key_in = (const float*)d_in[1];
    const float* value  = (const float*)d_in[2];
    const int*   mask   = (const int*)d_in[3];
    const float* Wq = (const float*)d_in[4];
    const float* bq = (const float*)d_in[5];
    const float* Wk = (const float*)d_in[6];
    const float* bk = (const float*)d_in[7];
    const float* Wv = (const float*)d_in[8];
    const float* bv = (const float*)d_in[9];
    const float* Wo = (const float*)d_in[10];
    const float* bo = (const float*)d_in[11];
    const float* syn = (const float*)d_in[12];
    const float* alp = (const float*)d_in[13];

    const long long XN = (long long)BB * SS * DD;   // 8M
    const long long WN = (long long)DD * DD;        // 1M
    const long long SN = (long long)HH * SS * SS;   // 16M

    _Float16* ws   = (_Float16*)d_ws;
    _Float16* xbuf = ws;
    _Float16* wqf  = ws + XN;
    _Float16* wkf  = wqf + WN;
    _Float16* wvf  = wkf + WN;
    _Float16* wof  = wvf + WN;
    _Float16* qws  = wof + WN;
    _Float16* kws  = qws + XN;
    _Float16* vTws = kws + XN;
    _Float16* synh = vTws + XN;
    unsigned long long* mbits = (unsigned long long*)(synh + SN);
    _Float16* ao   = xbuf;   // xbuf dead after v projection

    dim3 blk(256);
    dim3 ggrid(64, 8);       // 8192/128 x 1024/128

    // Convert query + all 4 weights + syn (scaled by (1-alpha)*log2e)
    CvtArgs a1;
    a1.src[0] = query;  a1.dst[0] = xbuf; a1.n[0] = XN; a1.scaled[0] = 0;
    a1.src[1] = Wq;     a1.dst[1] = wqf;  a1.n[1] = WN; a1.scaled[1] = 0;
    a1.src[2] = Wk;     a1.dst[2] = wkf;  a1.n[2] = WN; a1.scaled[2] = 0;
    a1.src[3] = Wv;     a1.dst[3] = wvf;  a1.n[3] = WN; a1.scaled[3] = 0;
    a1.src[4] = Wo;     a1.dst[4] = wof;  a1.n[4] = WN; a1.scaled[4] = 0;
    a1.src[5] = syn;    a1.dst[5] = synh; a1.n[5] = SN; a1.scaled[5] = 1;
    a1.alp = alp;
    cvt_f32_f16<<<dim3(8192, 6), blk, 0, stream>>>(a1);

    pack_mask<<<dim3(32768), blk, 0, stream>>>(mask, mbits);

    gemm_bt<0, true><<<ggrid, blk, 0, stream>>>(xbuf, wqf, bq, qws, alp);

    CvtArgs a2 = a1; a2.src[0] = key_in;
    cvt_f32_f16<<<dim3(4096, 1), blk, 0, stream>>>(a2);
    gemm_bt<3, false><<<ggrid, blk, 0, stream>>>(xbuf, wkf, bk, kws, alp);

    CvtArgs a3 = a1; a3.src[0] = value;
    cvt_f32_f16<<<dim3(4096, 1), blk, 0, stream>>>(a3);
    gemm_bt<1, false><<<ggrid, blk, 0, stream>>>(xbuf, wvf, bv, vTws, alp);

    attn_kernel<<<dim3(1024), blk, 0, stream>>>(qws, kws, vTws, mbits, synh, ao);

    gemm_bt<2, false><<<ggrid, blk, 0, stream>>>(ao, wof, bo, d_out, alp);
}

// Round 2
// 465.714 us; speedup vs baseline: 1.3184x; 1.0164x over previous
//
#include <hip/hip_runtime.h>
#include <stdint.h>

// Problem dims (fixed by reference): B=8, S=1024, D=1024, H=16, HD=64.
#define BB 8
#define SS 1024
#define DD 1024
#define HH 16
#define HDIM 64

typedef _Float16 half8 __attribute__((ext_vector_type(8)));
typedef _Float16 half4 __attribute__((ext_vector_type(4)));
typedef float   float4v __attribute__((ext_vector_type(4)));
typedef float   float8v __attribute__((ext_vector_type(8)));

#define AS1(p) ((__attribute__((address_space(1))) void*)(p))
#define AS3(p) ((__attribute__((address_space(3))) void*)(p))

#define LOG2E 1.4426950408889634f

#if __has_builtin(__builtin_amdgcn_exp2f)
#define EXP2(x) __builtin_amdgcn_exp2f(x)
#else
#define EXP2(x) __expf((x) * 0.6931471805599453f)
#endif

// ---------------------------------------------------------------------------
// f32 -> f16 conversion, multi-segment (grid.y selects segment), grid-stride.
// scaled[seg] != 0 => multiply by (1 - sigmoid(alp[0])) * log2(e)
// ---------------------------------------------------------------------------
struct CvtArgs {
    const float* src[8];
    _Float16*    dst[8];
    long long    n[8];
    int          scaled[8];
    const float* alp;
};

__global__ __launch_bounds__(256) void cvt_f32_f16(CvtArgs a) {
    const int seg = blockIdx.y;
    const long long n = a.n[seg];
    float s = 1.0f;
    if (a.scaled[seg]) s = (1.0f - 1.0f / (1.0f + __expf(-a.alp[0]))) * LOG2E;
    const float* __restrict__ src = a.src[seg];
    _Float16* __restrict__ dst = a.dst[seg];
    const long long stride = (long long)gridDim.x * 2048;   // blocks*256*8
    for (long long base = ((long long)blockIdx.x * 256 + threadIdx.x) * 8;
         base < n; base += stride) {
        float8v u = *(const float8v*)(src + base);
        half8 h;
#pragma unroll
        for (int i = 0; i < 8; ++i) h[i] = (_Float16)(u[i] * s);
        *(half8*)(dst + base) = h;
    }
}

// ---------------------------------------------------------------------------
// Pack mask (B,S,S) int32 -> bitmask (B,S,S/64) u64. One wave packs 64 keys.
// ---------------------------------------------------------------------------
__global__ __launch_bounds__(256) void pack_mask(const int* __restrict__ mask,
                                                 unsigned long long* __restrict__ bits) {
    long long gid = (long long)blockIdx.x * 256 + threadIdx.x;
    int m = mask[gid];
    unsigned long long bal = __ballot(m != 0);
    if ((threadIdx.x & 63) == 0) bits[gid >> 6] = bal;
}

// ---------------------------------------------------------------------------
// Shared GEMM core: C[m,n] = sum_k A[m,k]*W[n,k], 128x128 tile, BK=64,
// 4 waves (2x2 of 64x64), 16x16x32 f16 MFMA. T3 minimum 2-phase: LDS
// double-buffered, next tile's global_load_lds issued BEFORE compute of the
// current tile, one barrier per tile (its vmcnt(0) drain is covered by a
// full compute phase of MFMA+ds_read).
// ---------------------------------------------------------------------------
__device__ __forceinline__ void gemm_core(
    const _Float16* __restrict__ A, const _Float16* __restrict__ W,
    int m0, int n0, int wave, int lane, int wm, int wn,
    _Float16* As0, _Float16* Bs0, _Float16* As1, _Float16* Bs1,
    float4v (&acc)[4][4])
{
    constexpr int K = 1024, BK = 64;

    auto stage = [&](_Float16* Asb, _Float16* Bsb, int kt) {
#pragma unroll
        for (int i = 0; i < 4; ++i) {
            int flat = ((wave * 4 + i) * 64 + lane) * 8;  // halfword idx in tile
            int r = flat >> 6, c = flat & 63;
            const _Float16* ga = A + (long long)(m0 + r) * K + kt + c;
            const _Float16* gb = W + (long long)(n0 + r) * K + kt + c;
            __builtin_amdgcn_global_load_lds(AS1(ga), AS3(Asb + flat), 16, 0, 0);
            __builtin_amdgcn_global_load_lds(AS1(gb), AS3(Bsb + flat), 16, 0, 0);
        }
    };

    auto compute = [&](const _Float16* Asb, const _Float16* Bsb) {
#pragma unroll
        for (int kk = 0; kk < BK; kk += 32) {
            half8 af[4], bf[4];
#pragma unroll
            for (int t = 0; t < 4; ++t) {
                af[t] = *(const half8*)&Asb[(wm * 64 + t * 16 + (lane & 15)) * BK + kk + (lane >> 4) * 8];
                bf[t] = *(const half8*)&Bsb[(wn * 64 + t * 16 + (lane & 15)) * BK + kk + (lane >> 4) * 8];
            }
#pragma unroll
            for (int mt = 0; mt < 4; ++mt)
#pragma unroll
                for (int nt = 0; nt < 4; ++nt)
                    acc[mt][nt] = __builtin_amdgcn_mfma_f32_16x16x32_f16(af[mt], bf[nt], acc[mt][nt], 0, 0, 0);
        }
    };

    stage(As0, Bs0, 0);
    __syncthreads();
    for (int kt = 0; kt < K; kt += 2 * BK) {
        stage(As1, Bs1, kt + BK);        // DMA next tile overlaps compute
        compute(As0, Bs0);
        __syncthreads();                 // next ready; everyone done with 0
        if (kt + 2 * BK < K) stage(As0, Bs0, kt + 2 * BK);
        compute(As1, Bs1);
        __syncthreads();
    }
}

// ---------------------------------------------------------------------------
// Fused QKV projection GEMM. grid.z selects (A, W, bias, out, mode):
// mode 0: out f16 (B,H,S,HD) linear, scaled by sigmoid(alp)/8*log2e  (Q)
// mode 1: out f16 K tiled+swizzled: (bh,tile)[8KB], off=((key*128+hd*2)^((key&7)<<4))
// mode 2: out f16 V tiled+swizzled: (bh,tile)[8KB], off=((hd*128+sc*2)^((hd&15)<<3))
// Tiled layouts are consumed by attn's global_load_lds (linear DMA) + swizzled
// ds_read: the global image must equal the desired LDS image (both-sides rule).
// ---------------------------------------------------------------------------
struct QkvArgs {
    const _Float16* A[3];
    const _Float16* W[3];
    const float*    bias[3];
    _Float16*       out[3];
    int             mode[3];
    const float*    alp;
};

__global__ __launch_bounds__(256) void gemm_qkv(QkvArgs g) {
    constexpr int BM = 128, BK = 64;
    __shared__ _Float16 As0[BM * BK], Bs0[BM * BK];
    __shared__ _Float16 As1[BM * BK], Bs1[BM * BK];

    const int z = blockIdx.z;
    const int tid  = threadIdx.x;
    const int lane = tid & 63;
    const int wave = tid >> 6;
    const int wm = wave >> 1, wn = wave & 1;
    const int m0 = blockIdx.x * BM;
    const int n0 = blockIdx.y * BM;

    float4v acc[4][4] = {};
    gemm_core(g.A[z], g.W[z], m0, n0, wave, lane, wm, wn, As0, Bs0, As1, Bs1, acc);

    const int mode = g.mode[z];
    float qscale = 1.0f;
    if (mode == 0) qscale = 0.125f * LOG2E / (1.0f + __expf(-g.alp[0]));
    _Float16* o = g.out[z];
    const float* bias = g.bias[z];

    // Epilogue. C/D layout: row = (lane>>4)*4 + reg, col = lane&15.
#pragma unroll
    for (int mt = 0; mt < 4; ++mt) {
#pragma unroll
        for (int nt = 0; nt < 4; ++nt) {
            int n  = n0 + wn * 64 + nt * 16 + (lane & 15);
            int mb = m0 + wm * 64 + mt * 16 + (lane >> 4) * 4;
            float bn = bias[n];
            int b = mb >> 10, sI = mb & 1023, hI = n >> 6, hd = n & 63;
            if (mode == 0) {
                long long idx = ((long long)(b * 16 + hI) * 1024 + sI) * 64 + hd;
#pragma unroll
                for (int i = 0; i < 4; ++i)
                    o[idx + (long long)i * 64] = (_Float16)((acc[mt][nt][i] + bn) * qscale);
            } else if (mode == 1) {   // K tiled+swizzled
                long long tbase = (((long long)(b * 16 + hI)) * 16 + (sI >> 6)) * 4096;
#pragma unroll
                for (int i = 0; i < 4; ++i) {
                    int key = (sI & 63) + i;   // sI%4==0, stays within tile
                    o[tbase + (((key * 128 + hd * 2) ^ ((key & 7) << 4)) >> 1)] =
                        (_Float16)(acc[mt][nt][i] + bn);
                }
            } else {                  // V tiled+swizzled
                long long tbase = (((long long)(b * 16 + hI)) * 16 + (sI >> 6)) * 4096;
                int off = ((hd * 128 + (sI & 63) * 2) ^ ((hd & 15) << 3)) >> 1;
                half4 hv;
#pragma unroll
                for (int i = 0; i < 4; ++i) hv[i] = (_Float16)(acc[mt][nt][i] + bn);
                *(half4*)&o[tbase + off] = hv;   // 8B-aligned; swizzle bits >=3 preserve it
            }
        }
    }
}

// ---------------------------------------------------------------------------
// Output projection GEMM: f32 output row-major (M x 1024) -> d_out.
// ---------------------------------------------------------------------------
__global__ __launch_bounds__(256) void gemm_o(
    const _Float16* __restrict__ A,
    const _Float16* __restrict__ W,
    const float* __restrict__ bias,
    float* __restrict__ out)
{
    constexpr int BM = 128, BK = 64;
    __shared__ _Float16 As0[BM * BK], Bs0[BM * BK];
    __shared__ _Float16 As1[BM * BK], Bs1[BM * BK];

    const int tid  = threadIdx.x;
    const int lane = tid & 63;
    const int wave = tid >> 6;
    const int wm = wave >> 1, wn = wave & 1;
    const int m0 = blockIdx.x * BM;
    const int n0 = blockIdx.y * BM;

    float4v acc[4][4] = {};
    gemm_core(A, W, m0, n0, wave, lane, wm, wn, As0, Bs0, As1, Bs1, acc);

#pragma unroll
    for (int mt = 0; mt < 4; ++mt) {
#pragma unroll
        for (int nt = 0; nt < 4; ++nt) {
            int n  = n0 + wn * 64 + nt * 16 + (lane & 15);
            int mb = m0 + wm * 64 + mt * 16 + (lane >> 4) * 4;
            float bn = bias[n];
#pragma unroll
            for (int i = 0; i < 4; ++i)
                out[(long long)(mb + i) * 1024 + n] = acc[mt][nt][i] + bn;
        }
    }
}

// ---------------------------------------------------------------------------
// Flash attention (unchanged from R1 — verified). Grid: 1024 blocks
// (XCD-swizzled: each XCD owns one batch), 4 waves/block, each wave owns 32
// q-rows. K/V tiles (8KB) staged in LDS via global_load_lds, double-buffered,
// one barrier per tile. syn+mask register-prefetched one tile ahead. Softmax
// in exp2 domain; syn enters as QK^T C-in; row-sum l via ones-column MFMA;
// defer-max (THR=8).
// ---------------------------------------------------------------------------
__global__ __launch_bounds__(256) void attn_kernel(
    const _Float16* __restrict__ qw,   // (B*H, S, HD) f16 linear, pre-scaled
    const _Float16* __restrict__ ktl,  // (B*H, 16, 4096) K tiled+swizzled
    const _Float16* __restrict__ vtl,  // (B*H, 16, 4096) V tiled+swizzled
    const unsigned long long* __restrict__ mbits, // (B, S, 16) packed mask
    const _Float16* __restrict__ synh, // (H, S, S) f16, pre-scaled
    _Float16* __restrict__ ao)         // (B, S, D) f16
{
    __shared__ __align__(16) _Float16 KsA[4096];
    __shared__ __align__(16) _Float16 VsA[4096];
    __shared__ __align__(16) _Float16 KsB[4096];
    __shared__ __align__(16) _Float16 VsB[4096];

    const int tid  = threadIdx.x;
    const int lane = tid & 63;
    const int wave = tid >> 6;
    const int bid  = ((blockIdx.x & 7) << 7) | (blockIdx.x >> 3);
    const int b  = bid >> 7;
    const int h  = (bid >> 3) & 15;
    const int q0 = (bid & 7) * 128 + wave * 32;
    const int bh = b * 16 + h;

    half8 qf[2][2];
#pragma unroll
    for (int f = 0; f < 2; ++f) {
        const _Float16* qb = qw + ((long long)bh * SS + q0 + f * 16 + (lane & 15)) * HDIM + (lane >> 4) * 8;
        qf[f][0] = *(const half8*)qb;
        qf[f][1] = *(const half8*)(qb + 32);
    }

    float4v o[2][4] = {};
    float4v ol[2]   = {};
    float mrun[2] = {-3e38f, -3e38f};

    const _Float16* kgb = ktl + (long long)bh * 16 * 4096;
    const _Float16* vgb = vtl + (long long)bh * 16 * 4096;
    const unsigned long long* mb0 = mbits + ((long long)b * SS + q0 + (lane & 15)) * 16;
    const _Float16* syn0 = synh + ((long long)h * SS + q0 + (lane & 15)) * SS + ((lane >> 4) << 2);
    const _Float16* syn1 = syn0 + 16 * (long long)SS;

    const int tid8 = tid * 8;

    const int kswz = (lane & 7) << 4;
    const int kb0h = (((((lane & 15) << 7) + ((lane >> 4) << 4))      ) ^ kswz) >> 1;
    const int kb1h = (((((lane & 15) << 7) + ((lane >> 4) << 4)) + 64 ) ^ kswz) >> 1;
    int vbh[4];
#pragma unroll
    for (int ks = 0; ks < 4; ++ks)
        vbh[ks] = ((((lane & 15) << 7) + ks * 32 + ((lane >> 4) << 3)) ^ ((lane & 15) << 3)) >> 1;

    auto stage = [&](_Float16* Ksb, _Float16* Vsb, int t) {
        const _Float16* kg = kgb + t * 4096 + tid8;
        const _Float16* vg = vgb + t * 4096 + tid8;
        __builtin_amdgcn_global_load_lds(AS1(kg),        AS3(Ksb + tid8),        16, 0, 0);
        __builtin_amdgcn_global_load_lds(AS1(kg + 2048), AS3(Ksb + tid8 + 2048), 16, 0, 0);
        __builtin_amdgcn_global_load_lds(AS1(vg),        AS3(Vsb + tid8),        16, 0, 0);
        __builtin_amdgcn_global_load_lds(AS1(vg + 2048), AS3(Vsb + tid8 + 2048), 16, 0, 0);
    };

    half4 svA[2][4], svB[2][4];
    unsigned long long btA[2], btB[2];

    auto loadSyn = [&](int t, half4 (&sv)[2][4], unsigned long long (&bt)[2]) {
        bt[0] = mb0[t];
        bt[1] = mb0[256 + t];
        const int kb = t << 6;
#pragma unroll
        for (int ks = 0; ks < 4; ++ks) {
            sv[0][ks] = *(const half4*)(syn0 + kb + ks * 16);
            sv[1][ks] = *(const half4*)(syn1 + kb + ks * 16);
        }
    };

    const half4 vone = {(_Float16)1.f, (_Float16)1.f, (_Float16)1.f, (_Float16)1.f};

    auto compute = [&](const _Float16 (&Ks)[4096], const _Float16 (&Vs)[4096],
                       half4 (&sv)[2][4], unsigned long long (&bt)[2]) {
        float4v st[2][4];
#pragma unroll
        for (int ks = 0; ks < 4; ++ks) {
            half8 k0 = *(const half8*)&Ks[kb0h + ks * 1024];
            half8 k1 = *(const half8*)&Ks[kb1h + ks * 1024];
#pragma unroll
            for (int f = 0; f < 2; ++f) {
                float4v s;
#pragma unroll
                for (int i = 0; i < 4; ++i) s[i] = (float)sv[f][ks][i];
                s = __builtin_amdgcn_mfma_f32_16x16x32_f16(k0, qf[f][0], s, 0, 0, 0);
                s = __builtin_amdgcn_mfma_f32_16x16x32_f16(k1, qf[f][1], s, 0, 0, 0);
                st[f][ks] = s;
            }
        }
        half4 pf[2][4];
#pragma unroll
        for (int f = 0; f < 2; ++f) {
            const unsigned long long bits = bt[f];
            float tmax = -3e38f;
#pragma unroll
            for (int ks = 0; ks < 4; ++ks)
#pragma unroll
                for (int i = 0; i < 4; ++i) {
                    int pos = ks * 16 + ((lane >> 4) << 2) + i;
                    float sc = ((bits >> pos) & 1ull) ? st[f][ks][i] : -1e9f;
                    st[f][ks][i] = sc;
                    tmax = fmaxf(tmax, sc);
                }
            tmax = fmaxf(tmax, __shfl_xor(tmax, 16));
            tmax = fmaxf(tmax, __shfl_xor(tmax, 32));
            if (__any(tmax > mrun[f] + 8.0f)) {
                float mnew = fmaxf(mrun[f], tmax);
                float corr = EXP2(mrun[f] - mnew);
                float cr[4];
#pragma unroll
                for (int i = 0; i < 4; ++i) cr[i] = __shfl(corr, ((lane >> 4) << 2) + i);
#pragma unroll
                for (int n = 0; n < 4; ++n)
#pragma unroll
                    for (int i = 0; i < 4; ++i) o[f][n][i] *= cr[i];
#pragma unroll
                for (int i = 0; i < 4; ++i) ol[f][i] *= cr[i];
                mrun[f] = mnew;
            }
#pragma unroll
            for (int ks = 0; ks < 4; ++ks)
#pragma unroll
                for (int i = 0; i < 4; ++i)
                    pf[f][ks][i] = (_Float16)EXP2(st[f][ks][i] - mrun[f]);
        }
#pragma unroll
        for (int ks = 0; ks < 4; ++ks) {
            ol[0] = __builtin_amdgcn_mfma_f32_16x16x16f16(pf[0][ks], vone, ol[0], 0, 0, 0);
            ol[1] = __builtin_amdgcn_mfma_f32_16x16x16f16(pf[1][ks], vone, ol[1], 0, 0, 0);
#pragma unroll
            for (int n = 0; n < 4; ++n) {
                half4 vf = *(const half4*)&Vs[vbh[ks] + n * 1024];
                o[0][n] = __builtin_amdgcn_mfma_f32_16x16x16f16(pf[0][ks], vf, o[0][n], 0, 0, 0);
                o[1][n] = __builtin_amdgcn_mfma_f32_16x16x16f16(pf[1][ks], vf, o[1][n], 0, 0, 0);
            }
        }
    };

    stage(KsA, VsA, 0);
    loadSyn(0, svA, btA);
    __syncthreads();

    for (int t = 0; t < 16; t += 2) {
        stage(KsB, VsB, t + 1);
        loadSyn(t + 1, svB, btB);
        compute(KsA, VsA, svA, btA);
        __syncthreads();
        if (t + 2 < 16) {
            stage(KsA, VsA, t + 2);
            loadSyn(t + 2, svA, btA);
        }
        compute(KsB, VsB, svB, btB);
        __syncthreads();
    }

#pragma unroll
    for (int f = 0; f < 2; ++f) {
        float inv[4];
#pragma unroll
        for (int i = 0; i < 4; ++i) inv[i] = 1.0f / ol[f][i];
#pragma unroll
        for (int n = 0; n < 4; ++n)
#pragma unroll
            for (int i = 0; i < 4; ++i) {
                int qrow = q0 + f * 16 + (lane >> 4) * 4 + i;
                long long idx = ((long long)b * SS + qrow) * DD + h * 64 + n * 16 + (lane & 15);
                ao[idx] = (_Float16)(o[f][n][i] * inv[i]);
            }
    }
}

// ---------------------------------------------------------------------------
// Launcher. Two ws layouts chosen at runtime by ws_size:
// Fused path (ws >= 140 MB), f16 elements:
//   [0,8M)qx [8,16M)kx [16,24M)vx [24,28M)Wq..Wo [28,36M)q [36,44M)k
//   [44,52M)vT [52,68M)synh [68M,+1MB)mbits ; ao aliases qx.
// Fallback path (current 105 MB layout): xbuf reused for query/key/value/ao.
// ---------------------------------------------------------------------------
extern "C" void kernel_launch(void* const* d_in, const int* in_sizes, int n_in,
                              void* d_out, int out_size, void* d_ws, size_t ws_size,
                              hipStream_t stream) {
    const float* query  = (const float*)d_in[0];
    const float* key_in = (const float*)d_in[1];
    const float* value  = (const float*)d_in[2];
    const int*   mask   = (const int*)d_in[3];
    const float* Wq = (const float*)d_in[4];
    const float* bq = (const float*)d_in[5];
    const float* Wk = (const float*)d_in[6];
    const float* bk = (const float*)d_in[7];
    const float* Wv = (const float*)d_in[8];
    const float* bv = (const float*)d_in[9];
    const float* Wo = (const float*)d_in[10];
    const float* bo = (const float*)d_in[11];
    const float* syn = (const float*)d_in[12];
    const float* alp = (const float*)d_in[13];

    const long long XN = (long long)BB * SS * DD;   // 8M
    const long long WN = (long long)DD * DD;        // 1M
    const long long SN = (long long)HH * SS * SS;   // 16M

    _Float16* ws = (_Float16*)d_ws;
    dim3 blk(256);
    dim3 ggrid(64, 8);

    if (ws_size >= ((size_t)140 << 20)) {
        // ---- fused path ----
        _Float16* qx   = ws;
        _Float16* kx   = qx + XN;
        _Float16* vx   = kx + XN;
        _Float16* wqf  = vx + XN;
        _Float16* wkf  = wqf + WN;
        _Float16* wvf  = wkf + WN;
        _Float16* wof  = wvf + WN;
        _Float16* qws  = wof + WN;
        _Float16* kws  = qws + XN;
        _Float16* vTws = kws + XN;
        _Float16* synh = vTws + XN;
        unsigned long long* mbits = (unsigned long long*)(synh + SN);
        _Float16* ao = qx;   // qx dead after gemm_qkv

        CvtArgs a = {};
        a.src[0] = query;  a.dst[0] = qx;   a.n[0] = XN; a.scaled[0] = 0;
        a.src[1] = key_in; a.dst[1] = kx;   a.n[1] = XN; a.scaled[1] = 0;
        a.src[2] = value;  a.dst[2] = vx;   a.n[2] = XN; a.scaled[2] = 0;
        a.src[3] = Wq;     a.dst[3] = wqf;  a.n[3] = WN; a.scaled[3] = 0;
        a.src[4] = Wk;     a.dst[4] = wkf;  a.n[4] = WN; a.scaled[4] = 0;
        a.src[5] = Wv;     a.dst[5] = wvf;  a.n[5] = WN; a.scaled[5] = 0;
        a.src[6] = Wo;     a.dst[6] = wof;  a.n[6] = WN; a.scaled[6] = 0;
        a.src[7] = syn;    a.dst[7] = synh; a.n[7] = SN; a.scaled[7] = 1;
        a.alp = alp;
        cvt_f32_f16<<<dim3(2048, 8), blk, 0, stream>>>(a);

        pack_mask<<<dim3(32768), blk, 0, stream>>>(mask, mbits);

        QkvArgs g;
        g.A[0] = qx;  g.W[0] = wqf; g.bias[0] = bq; g.out[0] = qws;  g.mode[0] = 0;
        g.A[1] = kx;  g.W[1] = wkf; g.bias[1] = bk; g.out[1] = kws;  g.mode[1] = 1;
        g.A[2] = vx;  g.W[2] = wvf; g.bias[2] = bv; g.out[2] = vTws; g.mode[2] = 2;
        g.alp = alp;
        gemm_qkv<<<dim3(64, 8, 3), blk, 0, stream>>>(g);

        attn_kernel<<<dim3(1024), blk, 0, stream>>>(qws, kws, vTws, mbits, synh, ao);

        gemm_o<<<ggrid, blk, 0, stream>>>(ao, wof, bo, (float*)d_out);
    } else {
        // ---- fallback: sequential projections, xbuf reuse (105 MB) ----
        _Float16* xbuf = ws;
        _Float16* wqf  = ws + XN;
        _Float16* wkf  = wqf + WN;
        _Float16* wvf  = wkf + WN;
        _Float16* wof  = wvf + WN;
        _Float16* qws  = wof + WN;
        _Float16* kws  = qws + XN;
        _Float16* vTws = kws + XN;
        _Float16* synh = vTws + XN;
        unsigned long long* mbits = (unsigned long long*)(synh + SN);
        _Float16* ao = xbuf;

        CvtArgs a1 = {};
        a1.src[0] = query; a1.dst[0] = xbuf; a1.n[0] = XN; a1.scaled[0] = 0;
        a1.src[1] = Wq;    a1.dst[1] = wqf;  a1.n[1] = WN; a1.scaled[1] = 0;
        a1.src[2] = Wk;    a1.dst[2] = wkf;  a1.n[2] = WN; a1.scaled[2] = 0;
        a1.src[3] = Wv;    a1.dst[3] = wvf;  a1.n[3] = WN; a1.scaled[3] = 0;
        a1.src[4] = Wo;    a1.dst[4] = wof;  a1.n[4] = WN; a1.scaled[4] = 0;
        a1.src[5] = syn;   a1.dst[5] = synh; a1.n[5] = SN; a1.scaled[5] = 1;
        a1.alp = alp;
        cvt_f32_f16<<<dim3(2048, 6), blk, 0, stream>>>(a1);

        pack_mask<<<dim3(32768), blk, 0, stream>>>(mask, mbits);

        QkvArgs g;
        g.alp = alp;
        g.A[0] = xbuf; g.W[0] = wqf; g.bias[0] = bq; g.out[0] = qws; g.mode[0] = 0;
        gemm_qkv<<<dim3(64, 8, 1), blk, 0, stream>>>(g);

        CvtArgs a2 = a1; a2.src[0] = key_in;
        cvt_f32_f16<<<dim3(2048, 1), blk, 0, stream>>>(a2);
        g.A[0] = xbuf; g.W[0] = wkf; g.bias[0] = bk; g.out[0] = kws; g.mode[0] = 1;
        gemm_qkv<<<dim3(64, 8, 1), blk, 0, stream>>>(g);

        CvtArgs a3 = a1; a3.src[0] = value;
        cvt_f32_f16<<<dim3(2048, 1), blk, 0, stream>>>(a3);
        g.A[0] = xbuf; g.W[0] = wvf; g.bias[0] = bv; g.out[0] = vTws; g.mode[0] = 2;
        gemm_qkv<<<dim3(64, 8, 1), blk, 0, stream>>>(g);

        attn_kernel<<<dim3(1024), blk, 0, stream>>>(qws, kws, vTws, mbits, synh, ao);

        gemm_o<<<ggrid, blk, 0, stream>>>(ao, wof, bo, (float*)d_out);
    }
}

// Round 3
// 457.041 us; speedup vs baseline: 1.3434x; 1.0190x over previous
//
#include <hip/hip_runtime.h>
#include <stdint.h>

// Problem dims (fixed by reference): B=8, S=1024, D=1024, H=16, HD=64.
#define BB 8
#define SS 1024
#define DD 1024
#define HH 16
#define HDIM 64

typedef _Float16 half8 __attribute__((ext_vector_type(8)));
typedef _Float16 half4 __attribute__((ext_vector_type(4)));
typedef float   float4v __attribute__((ext_vector_type(4)));
typedef float   float8v __attribute__((ext_vector_type(8)));

#define AS1(p) ((__attribute__((address_space(1))) void*)(p))
#define AS3(p) ((__attribute__((address_space(3))) void*)(p))

#define LOG2E 1.4426950408889634f

#if __has_builtin(__builtin_amdgcn_exp2f)
#define EXP2(x) __builtin_amdgcn_exp2f(x)
#else
#define EXP2(x) __expf((x) * 0.6931471805599453f)
#endif

// ---------------------------------------------------------------------------
// f32 -> f16 conversion, multi-segment (grid.y selects segment), grid-stride.
// Only weights + syn now (inputs are consumed as f32 by the fused QKV GEMM).
// scaled[seg] != 0 => multiply by (1 - sigmoid(alp[0])) * log2(e)
// ---------------------------------------------------------------------------
struct CvtArgs {
    const float* src[8];
    _Float16*    dst[8];
    long long    n[8];
    int          scaled[8];
    const float* alp;
};

__global__ __launch_bounds__(256) void cvt_f32_f16(CvtArgs a) {
    const int seg = blockIdx.y;
    const long long n = a.n[seg];
    float s = 1.0f;
    if (a.scaled[seg]) s = (1.0f - 1.0f / (1.0f + __expf(-a.alp[0]))) * LOG2E;
    const float* __restrict__ src = a.src[seg];
    _Float16* __restrict__ dst = a.dst[seg];
    const long long stride = (long long)gridDim.x * 2048;   // blocks*256*8
    for (long long base = ((long long)blockIdx.x * 256 + threadIdx.x) * 8;
         base < n; base += stride) {
        float8v u = *(const float8v*)(src + base);
        half8 h;
#pragma unroll
        for (int i = 0; i < 8; ++i) h[i] = (_Float16)(u[i] * s);
        *(half8*)(dst + base) = h;
    }
}

// ---------------------------------------------------------------------------
// Pack mask (B,S,S) int32 -> bitmask (B,S,S/64) u64. One wave packs 64 keys.
// ---------------------------------------------------------------------------
__global__ __launch_bounds__(256) void pack_mask(const int* __restrict__ mask,
                                                 unsigned long long* __restrict__ bits) {
    long long gid = (long long)blockIdx.x * 256 + threadIdx.x;
    int m = mask[gid];
    unsigned long long bal = __ballot(m != 0);
    if ((threadIdx.x & 63) == 0) bits[gid >> 6] = bal;
}

// ---------------------------------------------------------------------------
// GEMM tile compute: 64x64 per wave (2x2 waves), 16x16x32 f16 MFMA, BK=64.
// ---------------------------------------------------------------------------
__device__ __forceinline__ void gemm_tile_compute(
    const _Float16* __restrict__ Asb, const _Float16* __restrict__ Bsb,
    int lane, int wm, int wn, float4v (&acc)[4][4])
{
    constexpr int BK = 64;
#pragma unroll
    for (int kk = 0; kk < BK; kk += 32) {
        half8 af[4], bf[4];
#pragma unroll
        for (int t = 0; t < 4; ++t) {
            af[t] = *(const half8*)&Asb[(wm * 64 + t * 16 + (lane & 15)) * BK + kk + (lane >> 4) * 8];
            bf[t] = *(const half8*)&Bsb[(wn * 64 + t * 16 + (lane & 15)) * BK + kk + (lane >> 4) * 8];
        }
#pragma unroll
        for (int mt = 0; mt < 4; ++mt)
#pragma unroll
            for (int nt = 0; nt < 4; ++nt)
                acc[mt][nt] = __builtin_amdgcn_mfma_f32_16x16x32_f16(af[mt], bf[nt], acc[mt][nt], 0, 0, 0);
    }
}

// ---------------------------------------------------------------------------
// Fused QKV projection GEMM, A consumed DIRECTLY as f32 (reg-stage + convert
// + ds_write; same f32->f16 RN rounding point as the old cvt pass -> numerics
// identical). W staged via global_load_lds. 2-phase double-buffered.
// XCD-aware tile swizzle: XCD g owns x-tiles [8g,8g+8) x all 8 y-tiles, so
// its A panel (2-4 MB) + W (2 MB) is ~L2-resident (was 16 MB thrash).
// grid.z selects (A, W, bias, out, mode):
// mode 0: out f16 (B,H,S,HD) linear, scaled by sigmoid(alp)/8*log2e  (Q)
// mode 1: out f16 K tiled+swizzled: (bh,tile)[8KB], off=((key*128+hd*2)^((key&7)<<4))
// mode 2: out f16 V tiled+swizzled: (bh,tile)[8KB], off=((hd*128+sc*2)^((hd&15)<<3))
// ---------------------------------------------------------------------------
struct QkvArgs {
    const float*    A[3];
    const _Float16* W[3];
    const float*    bias[3];
    _Float16*       out[3];
    int             mode[3];
    const float*    alp;
};

__global__ __launch_bounds__(256) void gemm_qkv(QkvArgs g) {
    constexpr int BM = 128, BK = 64, K = 1024;
    __shared__ _Float16 As0[BM * BK], Bs0[BM * BK];
    __shared__ _Float16 As1[BM * BK], Bs1[BM * BK];

    const int z = blockIdx.z;
    const int tid  = threadIdx.x;
    const int lane = tid & 63;
    const int wave = tid >> 6;
    const int wm = wave >> 1, wn = wave & 1;
    // XCD swizzle: id%8 = XCD (dispatch round-robin); XCD owns 8 consecutive
    // x-tiles across all y.
    const int id = blockIdx.x;
    const int xt = ((id & 7) << 3) | ((id >> 3) & 7);
    const int yt = id >> 6;
    const int m0 = xt * BM;
    const int n0 = yt * BM;

    const float*    __restrict__ A = g.A[z];
    const _Float16* __restrict__ W = g.W[z];

    float4v acc[4][4] = {};

    auto loadA = [&](float8v (&ar)[4], int kt) {
#pragma unroll
        for (int i = 0; i < 4; ++i) {
            int flat = ((wave * 4 + i) * 64 + lane) * 8;
            int r = flat >> 6, c = flat & 63;
            ar[i] = *(const float8v*)(A + (long long)(m0 + r) * K + kt + c);
        }
    };
    auto writeA = [&](_Float16* Asb, float8v (&ar)[4]) {
#pragma unroll
        for (int i = 0; i < 4; ++i) {
            int flat = ((wave * 4 + i) * 64 + lane) * 8;
            half8 h;
#pragma unroll
            for (int j = 0; j < 8; ++j) h[j] = (_Float16)ar[i][j];
            *(half8*)&Asb[flat] = h;
        }
    };
    auto stageW = [&](_Float16* Bsb, int kt) {
#pragma unroll
        for (int i = 0; i < 4; ++i) {
            int flat = ((wave * 4 + i) * 64 + lane) * 8;
            int r = flat >> 6, c = flat & 63;
            __builtin_amdgcn_global_load_lds(AS1(W + (long long)(n0 + r) * K + kt + c),
                                             AS3(Bsb + flat), 16, 0, 0);
        }
    };

    float8v arA[4], arB[4];
    loadA(arA, 0);
    stageW(Bs0, 0);
    writeA(As0, arA);
    __syncthreads();

    for (int kt = 0; kt < K; kt += 2 * BK) {
        loadA(arB, kt + BK);             // next A tile -> regs (latency under compute)
        stageW(Bs1, kt + BK);            // next W tile -> LDS DMA
        gemm_tile_compute(As0, Bs0, lane, wm, wn, acc);
        writeA(As1, arB);                // As1's old readers finished last barrier
        __syncthreads();
        const bool more = (kt + 2 * BK) < K;
        if (more) { loadA(arA, kt + 2 * BK); stageW(Bs0, kt + 2 * BK); }
        gemm_tile_compute(As1, Bs1, lane, wm, wn, acc);
        if (more) writeA(As0, arA);
        __syncthreads();
    }

    const int mode = g.mode[z];
    float qscale = 1.0f;
    if (mode == 0) qscale = 0.125f * LOG2E / (1.0f + __expf(-g.alp[0]));
    _Float16* o = g.out[z];
    const float* bias = g.bias[z];

    // Epilogue. C/D layout: row = (lane>>4)*4 + reg, col = lane&15.
#pragma unroll
    for (int mt = 0; mt < 4; ++mt) {
#pragma unroll
        for (int nt = 0; nt < 4; ++nt) {
            int n  = n0 + wn * 64 + nt * 16 + (lane & 15);
            int mb = m0 + wm * 64 + mt * 16 + (lane >> 4) * 4;
            float bn = bias[n];
            int b = mb >> 10, sI = mb & 1023, hI = n >> 6, hd = n & 63;
            if (mode == 0) {
                long long idx = ((long long)(b * 16 + hI) * 1024 + sI) * 64 + hd;
#pragma unroll
                for (int i = 0; i < 4; ++i)
                    o[idx + (long long)i * 64] = (_Float16)((acc[mt][nt][i] + bn) * qscale);
            } else if (mode == 1) {   // K tiled+swizzled
                long long tbase = (((long long)(b * 16 + hI)) * 16 + (sI >> 6)) * 4096;
#pragma unroll
                for (int i = 0; i < 4; ++i) {
                    int key = (sI & 63) + i;   // sI%4==0, stays within tile
                    o[tbase + (((key * 128 + hd * 2) ^ ((key & 7) << 4)) >> 1)] =
                        (_Float16)(acc[mt][nt][i] + bn);
                }
            } else {                  // V tiled+swizzled
                long long tbase = (((long long)(b * 16 + hI)) * 16 + (sI >> 6)) * 4096;
                int off = ((hd * 128 + (sI & 63) * 2) ^ ((hd & 15) << 3)) >> 1;
                half4 hv;
#pragma unroll
                for (int i = 0; i < 4; ++i) hv[i] = (_Float16)(acc[mt][nt][i] + bn);
                *(half4*)&o[tbase + off] = hv;   // 8B-aligned; swizzle bits >=3 preserve it
            }
        }
    }
}

// ---------------------------------------------------------------------------
// Output projection GEMM: A f16 (ao), W f16, f32 output row-major -> d_out.
// Same XCD swizzle; A staged via global_load_lds, 2-phase double-buffered.
// ---------------------------------------------------------------------------
__global__ __launch_bounds__(256) void gemm_o(
    const _Float16* __restrict__ A,
    const _Float16* __restrict__ W,
    const float* __restrict__ bias,
    float* __restrict__ out)
{
    constexpr int BM = 128, BK = 64, K = 1024;
    __shared__ _Float16 As0[BM * BK], Bs0[BM * BK];
    __shared__ _Float16 As1[BM * BK], Bs1[BM * BK];

    const int tid  = threadIdx.x;
    const int lane = tid & 63;
    const int wave = tid >> 6;
    const int wm = wave >> 1, wn = wave & 1;
    const int id = blockIdx.x;
    const int xt = ((id & 7) << 3) | ((id >> 3) & 7);
    const int yt = id >> 6;
    const int m0 = xt * BM;
    const int n0 = yt * BM;

    float4v acc[4][4] = {};

    auto stage = [&](_Float16* Asb, _Float16* Bsb, int kt) {
#pragma unroll
        for (int i = 0; i < 4; ++i) {
            int flat = ((wave * 4 + i) * 64 + lane) * 8;
            int r = flat >> 6, c = flat & 63;
            __builtin_amdgcn_global_load_lds(AS1(A + (long long)(m0 + r) * K + kt + c),
                                             AS3(Asb + flat), 16, 0, 0);
            __builtin_amdgcn_global_load_lds(AS1(W + (long long)(n0 + r) * K + kt + c),
                                             AS3(Bsb + flat), 16, 0, 0);
        }
    };

    stage(As0, Bs0, 0);
    __syncthreads();
    for (int kt = 0; kt < K; kt += 2 * BK) {
        stage(As1, Bs1, kt + BK);
        gemm_tile_compute(As0, Bs0, lane, wm, wn, acc);
        __syncthreads();
        if (kt + 2 * BK < K) stage(As0, Bs0, kt + 2 * BK);
        gemm_tile_compute(As1, Bs1, lane, wm, wn, acc);
        __syncthreads();
    }

#pragma unroll
    for (int mt = 0; mt < 4; ++mt) {
#pragma unroll
        for (int nt = 0; nt < 4; ++nt) {
            int n  = n0 + wn * 64 + nt * 16 + (lane & 15);
            int mb = m0 + wm * 64 + mt * 16 + (lane >> 4) * 4;
            float bn = bias[n];
#pragma unroll
            for (int i = 0; i < 4; ++i)
                out[(long long)(mb + i) * 1024 + n] = acc[mt][nt][i] + bn;
        }
    }
}

// ---------------------------------------------------------------------------
// Flash attention (unchanged from R1/R2 — verified at 124-126 us). Grid: 1024
// blocks (XCD-swizzled: each XCD owns one batch), 4 waves/block, each wave
// owns 32 q-rows. K/V tiles (8KB) staged in LDS via global_load_lds,
// double-buffered, one barrier per tile. syn+mask register-prefetched one
// tile ahead. Softmax in exp2 domain; syn enters as QK^T C-in; row-sum l via
// ones-column MFMA; defer-max (THR=8).
// ---------------------------------------------------------------------------
__global__ __launch_bounds__(256) void attn_kernel(
    const _Float16* __restrict__ qw,   // (B*H, S, HD) f16 linear, pre-scaled
    const _Float16* __restrict__ ktl,  // (B*H, 16, 4096) K tiled+swizzled
    const _Float16* __restrict__ vtl,  // (B*H, 16, 4096) V tiled+swizzled
    const unsigned long long* __restrict__ mbits, // (B, S, 16) packed mask
    const _Float16* __restrict__ synh, // (H, S, S) f16, pre-scaled
    _Float16* __restrict__ ao)         // (B, S, D) f16
{
    __shared__ __align__(16) _Float16 KsA[4096];
    __shared__ __align__(16) _Float16 VsA[4096];
    __shared__ __align__(16) _Float16 KsB[4096];
    __shared__ __align__(16) _Float16 VsB[4096];

    const int tid  = threadIdx.x;
    const int lane = tid & 63;
    const int wave = tid >> 6;
    const int bid  = ((blockIdx.x & 7) << 7) | (blockIdx.x >> 3);
    const int b  = bid >> 7;
    const int h  = (bid >> 3) & 15;
    const int q0 = (bid & 7) * 128 + wave * 32;
    const int bh = b * 16 + h;

    half8 qf[2][2];
#pragma unroll
    for (int f = 0; f < 2; ++f) {
        const _Float16* qb = qw + ((long long)bh * SS + q0 + f * 16 + (lane & 15)) * HDIM + (lane >> 4) * 8;
        qf[f][0] = *(const half8*)qb;
        qf[f][1] = *(const half8*)(qb + 32);
    }

    float4v o[2][4] = {};
    float4v ol[2]   = {};
    float mrun[2] = {-3e38f, -3e38f};

    const _Float16* kgb = ktl + (long long)bh * 16 * 4096;
    const _Float16* vgb = vtl + (long long)bh * 16 * 4096;
    const unsigned long long* mb0 = mbits + ((long long)b * SS + q0 + (lane & 15)) * 16;
    const _Float16* syn0 = synh + ((long long)h * SS + q0 + (lane & 15)) * SS + ((lane >> 4) << 2);
    const _Float16* syn1 = syn0 + 16 * (long long)SS;

    const int tid8 = tid * 8;

    const int kswz = (lane & 7) << 4;
    const int kb0h = (((((lane & 15) << 7) + ((lane >> 4) << 4))      ) ^ kswz) >> 1;
    const int kb1h = (((((lane & 15) << 7) + ((lane >> 4) << 4)) + 64 ) ^ kswz) >> 1;
    int vbh[4];
#pragma unroll
    for (int ks = 0; ks < 4; ++ks)
        vbh[ks] = ((((lane & 15) << 7) + ks * 32 + ((lane >> 4) << 3)) ^ ((lane & 15) << 3)) >> 1;

    auto stage = [&](_Float16* Ksb, _Float16* Vsb, int t) {
        const _Float16* kg = kgb + t * 4096 + tid8;
        const _Float16* vg = vgb + t * 4096 + tid8;
        __builtin_amdgcn_global_load_lds(AS1(kg),        AS3(Ksb + tid8),        16, 0, 0);
        __builtin_amdgcn_global_load_lds(AS1(kg + 2048), AS3(Ksb + tid8 + 2048), 16, 0, 0);
        __builtin_amdgcn_global_load_lds(AS1(vg),        AS3(Vsb + tid8),        16, 0, 0);
        __builtin_amdgcn_global_load_lds(AS1(vg + 2048), AS3(Vsb + tid8 + 2048), 16, 0, 0);
    };

    half4 svA[2][4], svB[2][4];
    unsigned long long btA[2], btB[2];

    auto loadSyn = [&](int t, half4 (&sv)[2][4], unsigned long long (&bt)[2]) {
        bt[0] = mb0[t];
        bt[1] = mb0[256 + t];
        const int kb = t << 6;
#pragma unroll
        for (int ks = 0; ks < 4; ++ks) {
            sv[0][ks] = *(const half4*)(syn0 + kb + ks * 16);
            sv[1][ks] = *(const half4*)(syn1 + kb + ks * 16);
        }
    };

    const half4 vone = {(_Float16)1.f, (_Float16)1.f, (_Float16)1.f, (_Float16)1.f};

    auto compute = [&](const _Float16 (&Ks)[4096], const _Float16 (&Vs)[4096],
                       half4 (&sv)[2][4], unsigned long long (&bt)[2]) {
        float4v st[2][4];
#pragma unroll
        for (int ks = 0; ks < 4; ++ks) {
            half8 k0 = *(const half8*)&Ks[kb0h + ks * 1024];
            half8 k1 = *(const half8*)&Ks[kb1h + ks * 1024];
#pragma unroll
            for (int f = 0; f < 2; ++f) {
                float4v s;
#pragma unroll
                for (int i = 0; i < 4; ++i) s[i] = (float)sv[f][ks][i];
                s = __builtin_amdgcn_mfma_f32_16x16x32_f16(k0, qf[f][0], s, 0, 0, 0);
                s = __builtin_amdgcn_mfma_f32_16x16x32_f16(k1, qf[f][1], s, 0, 0, 0);
                st[f][ks] = s;
            }
        }
        half4 pf[2][4];
#pragma unroll
        for (int f = 0; f < 2; ++f) {
            const unsigned long long bits = bt[f];
            float tmax = -3e38f;
#pragma unroll
            for (int ks = 0; ks < 4; ++ks)
#pragma unroll
                for (int i = 0; i < 4; ++i) {
                    int pos = ks * 16 + ((lane >> 4) << 2) + i;
                    float sc = ((bits >> pos) & 1ull) ? st[f][ks][i] : -1e9f;
                    st[f][ks][i] = sc;
                    tmax = fmaxf(tmax, sc);
                }
            tmax = fmaxf(tmax, __shfl_xor(tmax, 16));
            tmax = fmaxf(tmax, __shfl_xor(tmax, 32));
            if (__any(tmax > mrun[f] + 8.0f)) {
                float mnew = fmaxf(mrun[f], tmax);
                float corr = EXP2(mrun[f] - mnew);
                float cr[4];
#pragma unroll
                for (int i = 0; i < 4; ++i) cr[i] = __shfl(corr, ((lane >> 4) << 2) + i);
#pragma unroll
                for (int n = 0; n < 4; ++n)
#pragma unroll
                    for (int i = 0; i < 4; ++i) o[f][n][i] *= cr[i];
#pragma unroll
                for (int i = 0; i < 4; ++i) ol[f][i] *= cr[i];
                mrun[f] = mnew;
            }
#pragma unroll
            for (int ks = 0; ks < 4; ++ks)
#pragma unroll
                for (int i = 0; i < 4; ++i)
                    pf[f][ks][i] = (_Float16)EXP2(st[f][ks][i] - mrun[f]);
        }
#pragma unroll
        for (int ks = 0; ks < 4; ++ks) {
            ol[0] = __builtin_amdgcn_mfma_f32_16x16x16f16(pf[0][ks], vone, ol[0], 0, 0, 0);
            ol[1] = __builtin_amdgcn_mfma_f32_16x16x16f16(pf[1][ks], vone, ol[1], 0, 0, 0);
#pragma unroll
            for (int n = 0; n < 4; ++n) {
                half4 vf = *(const half4*)&Vs[vbh[ks] + n * 1024];
                o[0][n] = __builtin_amdgcn_mfma_f32_16x16x16f16(pf[0][ks], vf, o[0][n], 0, 0, 0);
                o[1][n] = __builtin_amdgcn_mfma_f32_16x16x16f16(pf[1][ks], vf, o[1][n], 0, 0, 0);
            }
        }
    };

    stage(KsA, VsA, 0);
    loadSyn(0, svA, btA);
    __syncthreads();

    for (int t = 0; t < 16; t += 2) {
        stage(KsB, VsB, t + 1);
        loadSyn(t + 1, svB, btB);
        compute(KsA, VsA, svA, btA);
        __syncthreads();
        if (t + 2 < 16) {
            stage(KsA, VsA, t + 2);
            loadSyn(t + 2, svA, btA);
        }
        compute(KsB, VsB, svB, btB);
        __syncthreads();
    }

#pragma unroll
    for (int f = 0; f < 2; ++f) {
        float inv[4];
#pragma unroll
        for (int i = 0; i < 4; ++i) inv[i] = 1.0f / ol[f][i];
#pragma unroll
        for (int n = 0; n < 4; ++n)
#pragma unroll
            for (int i = 0; i < 4; ++i) {
                int qrow = q0 + f * 16 + (lane >> 4) * 4 + i;
                long long idx = ((long long)b * SS + qrow) * DD + h * 64 + n * 16 + (lane & 15);
                ao[idx] = (_Float16)(o[f][n][i] * inv[i]);
            }
    }
}

// ---------------------------------------------------------------------------
// Launcher. Single path, fits the proven 105 MB workspace.
// ws layout (f16 elements):
//   [0,4M)     Wq,Wk,Wv,Wo f16 (1M each)
//   [4M,12M)   q  (B,H,S,HD)   pre-scaled by sigmoid(alpha)/8*log2e
//   [12M,20M)  k  tiled+swizzled (B*H,16,4096)
//   [20M,28M)  vT tiled+swizzled (B*H,16,4096)
//   [28M,44M)  synh (H,S,S) f16 pre-scaled by (1-alpha)*log2e
//   [44M,52M)  ao (B,S,D) f16
//   [52M,+1MB) mbits (B,S,16) u64
// Total = 104 MB + 1 MB = 105 MB (same as proven layout).
// ---------------------------------------------------------------------------
extern "C" void kernel_launch(void* const* d_in, const int* in_sizes, int n_in,
                              void* d_out, int out_size, void* d_ws, size_t ws_size,
                              hipStream_t stream) {
    const float* query  = (const float*)d_in[0];
    const float* key_in = (const float*)d_in[1];
    const float* value  = (const float*)d_in[2];
    const int*   mask   = (const int*)d_in[3];
    const float* Wq = (const float*)d_in[4];
    const float* bq = (const float*)d_in[5];
    const float* Wk = (const float*)d_in[6];
    const float* bk = (const float*)d_in[7];
    const float* Wv = (const float*)d_in[8];
    const float* bv = (const float*)d_in[9];
    const float* Wo = (const float*)d_in[10];
    const float* bo = (const float*)d_in[11];
    const float* syn = (const float*)d_in[12];
    const float* alp = (const float*)d_in[13];

    const long long XN = (long long)BB * SS * DD;   // 8M
    const long long WN = (long long)DD * DD;        // 1M
    const long long SN = (long long)HH * SS * SS;   // 16M

    _Float16* ws   = (_Float16*)d_ws;
    _Float16* wqf  = ws;
    _Float16* wkf  = wqf + WN;
    _Float16* wvf  = wkf + WN;
    _Float16* wof  = wvf + WN;
    _Float16* qws  = wof + WN;
    _Float16* kws  = qws + XN;
    _Float16* vTws = kws + XN;
    _Float16* synh = vTws + XN;
    _Float16* ao   = synh + SN;
    unsigned long long* mbits = (unsigned long long*)(ao + XN);

    dim3 blk(256);

    // Convert weights + syn only (inputs consumed as f32 by gemm_qkv).
    CvtArgs a = {};
    a.src[0] = Wq;  a.dst[0] = wqf;  a.n[0] = WN; a.scaled[0] = 0;
    a.src[1] = Wk;  a.dst[1] = wkf;  a.n[1] = WN; a.scaled[1] = 0;
    a.src[2] = Wv;  a.dst[2] = wvf;  a.n[2] = WN; a.scaled[2] = 0;
    a.src[3] = Wo;  a.dst[3] = wof;  a.n[3] = WN; a.scaled[3] = 0;
    a.src[4] = syn; a.dst[4] = synh; a.n[4] = SN; a.scaled[4] = 1;
    a.alp = alp;
    cvt_f32_f16<<<dim3(2048, 5), blk, 0, stream>>>(a);

    pack_mask<<<dim3(32768), blk, 0, stream>>>(mask, mbits);

    QkvArgs g;
    g.A[0] = query;  g.W[0] = wqf; g.bias[0] = bq; g.out[0] = qws;  g.mode[0] = 0;
    g.A[1] = key_in; g.W[1] = wkf; g.bias[1] = bk; g.out[1] = kws;  g.mode[1] = 1;
    g.A[2] = value;  g.W[2] = wvf; g.bias[2] = bv; g.out[2] = vTws; g.mode[2] = 2;
    g.alp = alp;
    gemm_qkv<<<dim3(512, 1, 3), blk, 0, stream>>>(g);

    attn_kernel<<<dim3(1024), blk, 0, stream>>>(qws, kws, vTws, mbits, synh, ao);

    gemm_o<<<dim3(512), blk, 0, stream>>>(ao, wof, bo, (float*)d_out);
}